// Round 16
// baseline (708.206 us; speedup 1.0000x reference)
//
#include <hip/hip_runtime.h>
#include <stdint.h>

#define NTOT 25920
#define OCV  1024
#define HW   1620
#define QPAD 1728         // 9 * 192 (also 18 * 96)
#define QROWS 1792        // qp/bsq padded rows (14 * 128)
#define NBLK 810          // 32-n granules
#define KSP  8

// per-b element strides in workspace arrays
#define MV2_STRIDE ((size_t)8 * NBLK * 4096)      // f16
#define MKP_STRIDE ((size_t)NTOT * 128)           // f16
#define QP_STRIDE  ((size_t)QROWS * 128)          // f16
#define BSQ_STRIDE ((size_t)QROWS)                // f32
#define P_STRIDE   ((size_t)NBLK * QPAD * 32)     // f16
#define PO_STRIDE  ((size_t)KSP * OCV * QPAD)     // f16
#define LP_STRIDE  ((size_t)405 * QPAD)           // f32
#define LQ_STRIDE  ((size_t)QPAD)                 // f32

typedef _Float16 f16x8 __attribute__((ext_vector_type(8)));
typedef _Float16 f16x4 __attribute__((ext_vector_type(4)));
typedef float f32x4 __attribute__((ext_vector_type(4)));

__device__ __forceinline__ void gload_lds16(const void* g, void* l) {
  __builtin_amdgcn_global_load_lds(
      (const __attribute__((address_space(1))) uint32_t*)g,
      (__attribute__((address_space(3))) uint32_t*)l, 16, 0, 0);
}

// ---- prep: MV fp32 -> mv2[b][vblk8][nblk810][128v][32n] fp16, pre-swizzled.
__global__ __launch_bounds__(256) void k_prep_mv2(const float* __restrict__ mv,
                                                  _Float16* __restrict__ mv2,
                                                  int bBase) {
  const int nblk = blockIdx.x, vblk = blockIdx.y, bg = blockIdx.z, t = threadIdx.x;
  const float* mvb = mv + (size_t)(bBase + bg) * OCV * NTOT;
  _Float16* outb = mv2 + (size_t)bg * MV2_STRIDE + ((size_t)(vblk * NBLK + nblk)) * 4096;
  #pragma unroll
  for (int r = 0; r < 2; ++r) {
    int idx = t + r * 256;
    int row = idx >> 2, s = idx & 3, j = s ^ ((row >> 1) & 3);
    const float* src = mvb + ((size_t)(vblk * 128 + row)) * NTOT + nblk * 32 + j * 8;
    float4 a = *((const float4*)src);
    float4 c = *((const float4*)(src + 4));
    f16x8 o;
    o[0]=(_Float16)a.x; o[1]=(_Float16)a.y; o[2]=(_Float16)a.z; o[3]=(_Float16)a.w;
    o[4]=(_Float16)c.x; o[5]=(_Float16)c.y; o[6]=(_Float16)c.z; o[7]=(_Float16)c.w;
    *((f16x8*)(outb + (size_t)idx * 8)) = o;
  }
}

// ---- prep: MK -> mkp[b][n][128k] fp16 (rows mk ; mk^2)
__global__ __launch_bounds__(256) void k_prep_mk(const float* __restrict__ mk,
                                                 _Float16* __restrict__ mkp,
                                                 int bBase) {
  __shared__ _Float16 LT[64 * 128];
  const int bg = blockIdx.y;
  const float* mkb = mk + (size_t)(bBase + bg) * 64 * NTOT;
  _Float16* mkpb = mkp + (size_t)bg * MKP_STRIDE;
  int n0 = blockIdx.x * 64;
  int c4 = threadIdx.x >> 6, nl = threadIdx.x & 63;
  for (int c = c4; c < 64; c += 4) {
    float v = mkb[(size_t)c * NTOT + n0 + nl];
    LT[nl * 128 + c]      = (_Float16)v;
    LT[nl * 128 + 64 + c] = (_Float16)(v * v);
  }
  __syncthreads();
  #pragma unroll
  for (int k = 0; k < 4; ++k) {
    int idx = threadIdx.x + 256 * k;
    int n = idx >> 4, c16 = idx & 15;
    *((uint4*)(mkpb + ((size_t)(n0 + n)) * 128 + c16 * 8)) =
        *((const uint4*)(&LT[n * 128 + c16 * 8]));
  }
}

// ---- prep: Q -> qp[b][q][128k] fp16, bsq fp32; rows [HW, QROWS) zero
__global__ __launch_bounds__(128) void k_prep_q(const float* __restrict__ qk,
                                                const float* __restrict__ qe,
                                                _Float16* __restrict__ qp,
                                                float* __restrict__ bsq,
                                                int bBase) {
  __shared__ _Float16 LT[128 * 128];
  const int bg = blockIdx.y;
  const float* qkb = qk + (size_t)(bBase + bg) * 64 * HW;
  const float* qeb = qe + (size_t)(bBase + bg) * 64 * HW;
  _Float16* qpb = qp + (size_t)bg * QP_STRIDE;
  int q0 = blockIdx.x * 128;
  int t = threadIdx.x;
  int q = q0 + t;
  bool valid = q < HW;
  float acc = 0.f;
  for (int c = 0; c < 64; ++c) {
    float a = valid ? qkb[(size_t)c * HW + q] : 0.f;
    float e = valid ? qeb[(size_t)c * HW + q] : 0.f;
    LT[t * 128 + c]      = (_Float16)(2.f * a * e);
    LT[t * 128 + 64 + c] = (_Float16)(-e);
    acc += e * a * a;
  }
  bsq[(size_t)bg * BSQ_STRIDE + q] = acc;
  __syncthreads();
  #pragma unroll
  for (int k = 0; k < 16; ++k) {
    int idx = t + 128 * k;
    int qq = idx >> 4, c16 = idx & 15;
    *((uint4*)(qpb + ((size_t)(q0 + qq)) * 128 + c16 * 8)) =
        *((const uint4*)(&LT[qq * 128 + c16 * 8]));
  }
}

// ---- S-kernel: P[b][nblk][q][32n] fp16 (swizzled) + lpart colsums.
// 18 q-tiles of 96 (QPAD=1728). XCD co-location: xcd = wgid&7 owns a
// contiguous 51/50-nunit range.
__global__ __launch_bounds__(256) void k_S(const _Float16* __restrict__ mkp,
                                           const _Float16* __restrict__ qp,
                                           const float* __restrict__ bsq,
                                           const float* __restrict__ ms,
                                           _Float16* __restrict__ P,
                                           float* __restrict__ lpart,
                                           int bBase) {
  const int wgid = blockIdx.x;
  const int xcd = wgid & 7;
  int kk = wgid >> 3;                  // [0, 918*NB)
  const int bg = kk / 918;
  kk -= bg * 918;
  const int nloc = kk / 18, qt = kk % 18;
  const int cntn = (xcd < 5) ? 51 : 50;
  if (nloc >= cntn) return;
  const int base = (xcd < 5) ? xcd * 51 : 255 + (xcd - 5) * 50;
  const int nunit = base + nloc;
  const int n0 = nunit * 64, q0 = qt * 96;

  const _Float16* mkpb = mkp + (size_t)bg * MKP_STRIDE;
  const _Float16* qpb  = qp + (size_t)bg * QP_STRIDE;
  const float* bsqb    = bsq + (size_t)bg * BSQ_STRIDE;
  const float* msb     = ms + (size_t)(bBase + bg) * NTOT;
  _Float16* Pb         = P + (size_t)bg * P_STRIDE;
  float* lpb           = lpart + (size_t)bg * LP_STRIDE;

  const int t = threadIdx.x;
  const int w = t >> 6, l = t & 63, l15 = l & 15, g = l >> 4;
  const int ns = w >> 1, qs = w & 1;

  f16x8 qf[3][4]; float bq[3];
  #pragma unroll
  for (int qi = 0; qi < 3; ++qi) {
    int q = q0 + qs * 48 + qi * 16 + l15;
    #pragma unroll
    for (int ks = 0; ks < 4; ++ks)
      qf[qi][ks] = *((const f16x8*)(qpb + (size_t)q * 128 + (ks * 4 + g) * 8));
    bq[qi] = bsqb[q];
  }
  f16x8 af[2][4];
  #pragma unroll
  for (int nt = 0; nt < 2; ++nt) {
    int n = n0 + ns * 32 + nt * 16 + l15;
    #pragma unroll
    for (int ks = 0; ks < 4; ++ks)
      af[nt][ks] = *((const f16x8*)(mkpb + (size_t)n * 128 + (ks * 4 + g) * 8));
  }
  f32x4 sacc[2][3];
  #pragma unroll
  for (int nt = 0; nt < 2; ++nt)
    #pragma unroll
    for (int qi = 0; qi < 3; ++qi) sacc[nt][qi] = (f32x4)0.f;
  #pragma unroll
  for (int ks = 0; ks < 4; ++ks)
    #pragma unroll
    for (int nt = 0; nt < 2; ++nt)
      #pragma unroll
      for (int qi = 0; qi < 3; ++qi)
        sacc[nt][qi] = __builtin_amdgcn_mfma_f32_16x16x32_f16(af[nt][ks], qf[qi][ks], sacc[nt][qi], 0, 0, 0);

  const float K = 0.125f * 1.44269504f;
  float4 mm[2];
  #pragma unroll
  for (int nt = 0; nt < 2; ++nt)
    mm[nt] = *((const float4*)(msb + n0 + ns * 32 + nt * 16 + g * 4));
  float psum[3] = {0.f, 0.f, 0.f};
  #pragma unroll
  for (int nt = 0; nt < 2; ++nt) {
    float m0 = mm[nt].x * K, m1 = mm[nt].y * K, m2 = mm[nt].z * K, m3 = mm[nt].w * K;
    #pragma unroll
    for (int qi = 0; qi < 3; ++qi) {
      int q = q0 + qs * 48 + qi * 16 + l15;
      float bqv = bq[qi];
      float p0 = exp2f((sacc[nt][qi][0] - bqv) * m0);
      float p1 = exp2f((sacc[nt][qi][1] - bqv) * m1);
      float p2 = exp2f((sacc[nt][qi][2] - bqv) * m2);
      float p3 = exp2f((sacc[nt][qi][3] - bqv) * m3);
      psum[qi] += (p0 + p1) + (p2 + p3);
      f16x4 ph;
      ph[0]=(_Float16)p0; ph[1]=(_Float16)p1; ph[2]=(_Float16)p2; ph[3]=(_Float16)p3;
      int nblkP = nunit * 2 + ns;
      int s_lin = nt * 2 + (g >> 1);
      int s = s_lin ^ ((q >> 1) & 3);
      *((f16x4*)(Pb + ((size_t)nblkP * QPAD + q) * 32 + s * 8 + (g & 1) * 4)) = ph;
    }
  }
  #pragma unroll
  for (int qi = 0; qi < 3; ++qi) {
    psum[qi] += __shfl_xor(psum[qi], 16);
    psum[qi] += __shfl_xor(psum[qi], 32);
  }
  __shared__ float LR[2][96];
  if (g == 0) {
    #pragma unroll
    for (int qi = 0; qi < 3; ++qi) LR[ns][qs * 48 + qi * 16 + l15] = psum[qi];
  }
  __syncthreads();
  if (t < 96) lpb[(size_t)nunit * QPAD + q0 + t] = LR[0][t] + LR[1][t];
}

// ---- lsum: l[b][q] = sum over 405 partials
__global__ __launch_bounds__(256) void k_lsum(const float* __restrict__ lpart,
                                              float* __restrict__ lout) {
  const int bg = blockIdx.y;
  int q = blockIdx.x * 256 + threadIdx.x;
  if (q >= QPAD) return;
  const float* lpb = lpart + (size_t)bg * LP_STRIDE;
  float s = 0.f;
  #pragma unroll 5
  for (int i = 0; i < 405; ++i) s += lpb[(size_t)i * QPAD + q];
  lout[(size_t)bg * LQ_STRIDE + q] = s;
}

// ---- RO: GEMM pO[b][ksp][1024v][1728q] fp16 = MV x P over ksp's K-split.
// R12 2-phase schedule, WIDER WAVE TILE: block 128v x 192q, 4 waves (2v x 2q),
// wave = 64v x 96q (acc[4][6]); 24 MFMA per 10 ds_read_b128 = 38 FLOP/LDS-byte
// (R12: 27). LDS dbuf 40KB. ksp = wgid&7 (XCD co-location).
__global__ __launch_bounds__(256) void k_RO(const _Float16* __restrict__ mv2,
                                            const _Float16* __restrict__ P,
                                            _Float16* __restrict__ pO) {
  const int wgid = blockIdx.x;
  const int ksp = wgid & 7;
  int kk = wgid >> 3;                  // [0, 72*NB)
  const int bg = kk / 72;
  kk -= bg * 72;
  const int qt = kk % 9, vblk = kk / 9;
  const int mn = (ksp < 2) ? ksp : 2;
  const int start = ksp * 101 + mn;
  const int cnt = 101 + (ksp < 2 ? 1 : 0);

  const _Float16* mv2b = mv2 + (size_t)bg * MV2_STRIDE;
  const _Float16* Pb   = P + (size_t)bg * P_STRIDE;
  _Float16* pOb        = pO + (size_t)bg * PO_STRIDE;

  const int t = threadIdx.x;
  const int w = t >> 6, l = t & 63, l15 = l & 15, g = l >> 4;
  const int wv = w >> 1, wq = w & 1;

  __shared__ _Float16 As[2][4096];   // [128v][32n], pre-swizzled src, linear dest
  __shared__ _Float16 Bs[2][6144];   // [192q][32n]

  f32x4 acc[4][6];
  #pragma unroll
  for (int i = 0; i < 4; ++i)
    #pragma unroll
    for (int j = 0; j < 6; ++j) acc[i][j] = (f32x4)0.f;

  auto stage = [&](int nblk, int buf) {
    const char* a = (const char*)(mv2b + ((size_t)(vblk * NBLK + nblk)) * 4096);
    char* da = (char*)As[buf];
    gload_lds16(a + t * 16, da + t * 16);
    gload_lds16(a + 4096 + t * 16, da + 4096 + t * 16);
    const char* bsrc = (const char*)(Pb + ((size_t)nblk * QPAD + qt * 192) * 32);
    char* db = (char*)Bs[buf];
    gload_lds16(bsrc + t * 16, db + t * 16);
    gload_lds16(bsrc + 4096 + t * 16, db + 4096 + t * 16);
    gload_lds16(bsrc + 8192 + t * 16, db + 8192 + t * 16);
  };

  stage(start, 0);
  asm volatile("s_waitcnt vmcnt(0)" ::: "memory");
  __builtin_amdgcn_s_barrier();
  __builtin_amdgcn_sched_barrier(0);

  for (int it = 0; it < cnt; ++it) {
    const int cur = it & 1, nxt = cur ^ 1;
    if (it + 1 < cnt) stage(start + it + 1, nxt);
    const _Float16* Ac = As[cur];
    const _Float16* Bc = Bs[cur];
    f16x8 av[4], bp[6];
    #pragma unroll
    for (int i = 0; i < 4; ++i) {
      int v_loc = wv * 64 + i * 16 + l15;
      av[i] = *((const f16x8*)(Ac + v_loc * 32 + ((g ^ ((v_loc >> 1) & 3)) * 8)));
    }
    #pragma unroll
    for (int j = 0; j < 6; ++j) {
      int q_loc = wq * 96 + j * 16 + l15;
      bp[j] = *((const f16x8*)(Bc + q_loc * 32 + ((g ^ ((q_loc >> 1) & 3)) * 8)));
    }
    #pragma unroll
    for (int i = 0; i < 4; ++i)
      #pragma unroll
      for (int j = 0; j < 6; ++j)
        acc[i][j] = __builtin_amdgcn_mfma_f32_16x16x32_f16(av[i], bp[j], acc[i][j], 0, 0, 0);
    asm volatile("s_waitcnt vmcnt(0) lgkmcnt(0)" ::: "memory");
    __builtin_amdgcn_s_barrier();
    __builtin_amdgcn_sched_barrier(0);
  }

  #pragma unroll
  for (int i = 0; i < 4; ++i) {
    #pragma unroll
    for (int j = 0; j < 6; ++j) {
      int qg = qt * 192 + wq * 96 + j * 16 + l15;
      #pragma unroll
      for (int r = 0; r < 4; ++r) {
        int v = vblk * 128 + wv * 64 + i * 16 + g * 4 + r;
        pOb[((size_t)ksp * OCV + v) * QPAD + qg] = (_Float16)acc[i][j][r];
      }
    }
  }
}

// ---- final: out[b][v][q] = sum_sp pO / l[q]
__global__ __launch_bounds__(256) void k_final(const _Float16* __restrict__ pO,
                                               const float* __restrict__ lq,
                                               float* __restrict__ out,
                                               int bBase) {
  int i = blockIdx.x * 256 + threadIdx.x;
  int q = i % HW;
  int rest = i / HW;
  int v = rest & (OCV - 1);
  int bg = rest >> 10;
  const _Float16* pOb = pO + (size_t)bg * PO_STRIDE;
  float s = 0.f;
  #pragma unroll
  for (int sp = 0; sp < KSP; ++sp)
    s += (float)pOb[((size_t)sp * OCV + v) * QPAD + q];
  out[((size_t)(bBase + bg) * OCV + v) * HW + q] = s / lq[(size_t)bg * LQ_STRIDE + q];
}

static void run_batch(const float* qk, const float* qe, const float* mk,
                      const float* ms, const float* mv, float* out,
                      char* ws, int bBase, int NB, hipStream_t stream) {
  char* p = ws;
  _Float16* mv2 = (_Float16*)p; p += (size_t)NB * MV2_STRIDE * 2;
  _Float16* mkp = (_Float16*)p; p += (size_t)NB * MKP_STRIDE * 2;
  _Float16* qp  = (_Float16*)p; p += (size_t)NB * QP_STRIDE * 2;
  float* bsq    = (float*)p;    p += (size_t)NB * BSQ_STRIDE * 4;
  _Float16* P   = (_Float16*)p; p += (size_t)NB * P_STRIDE * 2;
  _Float16* pO  = (_Float16*)p; p += (size_t)NB * PO_STRIDE * 2;
  float* lpart  = (float*)p;    p += (size_t)NB * LP_STRIDE * 4;
  float* lq     = (float*)p;

  k_prep_mv2<<<dim3(NBLK, 8, NB), 256, 0, stream>>>(mv, mv2, bBase);
  k_prep_mk<<<dim3(405, NB), 256, 0, stream>>>(mk, mkp, bBase);
  k_prep_q<<<dim3(14, NB), 128, 0, stream>>>(qk, qe, qp, bsq, bBase);
  k_S<<<8 * 918 * NB, 256, 0, stream>>>(mkp, qp, bsq, ms, P, lpart, bBase);
  k_lsum<<<dim3(7, NB), 256, 0, stream>>>(lpart, lq);
  k_RO<<<8 * 72 * NB, 256, 0, stream>>>(mv2, P, pO);
  k_final<<<6480 * NB, 256, 0, stream>>>(pO, lq, out, bBase);
}

extern "C" void kernel_launch(void* const* d_in, const int* in_sizes, int n_in,
                              void* d_out, int out_size, void* d_ws, size_t ws_size,
                              hipStream_t stream) {
  const float* qk = (const float*)d_in[0];
  const float* qe = (const float*)d_in[1];
  const float* mk = (const float*)d_in[2];
  const float* ms = (const float*)d_in[3];
  const float* mv = (const float*)d_in[4];
  float* out = (float*)d_out;

  const size_t per_b = MV2_STRIDE * 2 + MKP_STRIDE * 2 + QP_STRIDE * 2 + BSQ_STRIDE * 4
                     + P_STRIDE * 2 + PO_STRIDE * 2 + LP_STRIDE * 4 + LQ_STRIDE * 4;
  if (ws_size >= 2 * per_b) {
    run_batch(qk, qe, mk, ms, mv, out, (char*)d_ws, 0, 2, stream);
  } else if (ws_size >= per_b) {
    run_batch(qk, qe, mk, ms, mv, out, (char*)d_ws, 0, 1, stream);
    run_batch(qk, qe, mk, ms, mv, out, (char*)d_ws, 1, 1, stream);
  }
}

// Round 17
// 486.163 us; speedup vs baseline: 1.4567x; 1.4567x over previous
//
#include <hip/hip_runtime.h>
#include <stdint.h>

#define NTOT 25920
#define OCV  1024
#define HW   1620
#define QPAD 1632         // 17 * 96
#define QROWS 1664        // qp/bsq padded rows (13 * 128)
#define NBLK 810          // 32-n granules
#define KSP  4

// per-b element strides in workspace arrays
#define MV2_STRIDE ((size_t)8 * NBLK * 4096)      // f16
#define MKP_STRIDE ((size_t)NTOT * 128)           // f16
#define QP_STRIDE  ((size_t)QROWS * 128)          // f16
#define BSQ_STRIDE ((size_t)QROWS)                // f32
#define P_STRIDE   ((size_t)NBLK * QPAD * 32)     // f16
#define PO_STRIDE  ((size_t)KSP * OCV * QPAD)     // f16
#define LP_STRIDE  ((size_t)405 * QPAD)           // f32
#define LQ_STRIDE  ((size_t)QPAD)                 // f32

typedef _Float16 f16x8 __attribute__((ext_vector_type(8)));
typedef _Float16 f16x4 __attribute__((ext_vector_type(4)));
typedef float f32x4 __attribute__((ext_vector_type(4)));

__device__ __forceinline__ void gload_lds16(const void* g, void* l) {
  __builtin_amdgcn_global_load_lds(
      (const __attribute__((address_space(1))) uint32_t*)g,
      (__attribute__((address_space(3))) uint32_t*)l, 16, 0, 0);
}

// ---- prep: MV fp32 -> mv2[b][vblk8][nblk810][128v][32n] fp16, pre-swizzled.
__global__ __launch_bounds__(256) void k_prep_mv2(const float* __restrict__ mv,
                                                  _Float16* __restrict__ mv2,
                                                  int bBase) {
  const int nblk = blockIdx.x, vblk = blockIdx.y, bg = blockIdx.z, t = threadIdx.x;
  const float* mvb = mv + (size_t)(bBase + bg) * OCV * NTOT;
  _Float16* outb = mv2 + (size_t)bg * MV2_STRIDE + ((size_t)(vblk * NBLK + nblk)) * 4096;
  #pragma unroll
  for (int r = 0; r < 2; ++r) {
    int idx = t + r * 256;
    int row = idx >> 2, s = idx & 3, j = s ^ ((row >> 1) & 3);
    const float* src = mvb + ((size_t)(vblk * 128 + row)) * NTOT + nblk * 32 + j * 8;
    float4 a = *((const float4*)src);
    float4 c = *((const float4*)(src + 4));
    f16x8 o;
    o[0]=(_Float16)a.x; o[1]=(_Float16)a.y; o[2]=(_Float16)a.z; o[3]=(_Float16)a.w;
    o[4]=(_Float16)c.x; o[5]=(_Float16)c.y; o[6]=(_Float16)c.z; o[7]=(_Float16)c.w;
    *((f16x8*)(outb + (size_t)idx * 8)) = o;
  }
}

// ---- prep: MK -> mkp[b][n][128k] fp16 (rows mk ; mk^2)
__global__ __launch_bounds__(256) void k_prep_mk(const float* __restrict__ mk,
                                                 _Float16* __restrict__ mkp,
                                                 int bBase) {
  __shared__ _Float16 LT[64 * 128];
  const int bg = blockIdx.y;
  const float* mkb = mk + (size_t)(bBase + bg) * 64 * NTOT;
  _Float16* mkpb = mkp + (size_t)bg * MKP_STRIDE;
  int n0 = blockIdx.x * 64;
  int c4 = threadIdx.x >> 6, nl = threadIdx.x & 63;
  for (int c = c4; c < 64; c += 4) {
    float v = mkb[(size_t)c * NTOT + n0 + nl];
    LT[nl * 128 + c]      = (_Float16)v;
    LT[nl * 128 + 64 + c] = (_Float16)(v * v);
  }
  __syncthreads();
  #pragma unroll
  for (int k = 0; k < 4; ++k) {
    int idx = threadIdx.x + 256 * k;
    int n = idx >> 4, c16 = idx & 15;
    *((uint4*)(mkpb + ((size_t)(n0 + n)) * 128 + c16 * 8)) =
        *((const uint4*)(&LT[n * 128 + c16 * 8]));
  }
}

// ---- prep: Q -> qp[b][q][128k] fp16, bsq fp32; rows [HW, QROWS) zero
__global__ __launch_bounds__(128) void k_prep_q(const float* __restrict__ qk,
                                                const float* __restrict__ qe,
                                                _Float16* __restrict__ qp,
                                                float* __restrict__ bsq,
                                                int bBase) {
  __shared__ _Float16 LT[128 * 128];
  const int bg = blockIdx.y;
  const float* qkb = qk + (size_t)(bBase + bg) * 64 * HW;
  const float* qeb = qe + (size_t)(bBase + bg) * 64 * HW;
  _Float16* qpb = qp + (size_t)bg * QP_STRIDE;
  int q0 = blockIdx.x * 128;
  int t = threadIdx.x;
  int q = q0 + t;
  bool valid = q < HW;
  float acc = 0.f;
  for (int c = 0; c < 64; ++c) {
    float a = valid ? qkb[(size_t)c * HW + q] : 0.f;
    float e = valid ? qeb[(size_t)c * HW + q] : 0.f;
    LT[t * 128 + c]      = (_Float16)(2.f * a * e);
    LT[t * 128 + 64 + c] = (_Float16)(-e);
    acc += e * a * a;
  }
  bsq[(size_t)bg * BSQ_STRIDE + q] = acc;
  __syncthreads();
  #pragma unroll
  for (int k = 0; k < 16; ++k) {
    int idx = t + 128 * k;
    int qq = idx >> 4, c16 = idx & 15;
    *((uint4*)(qpb + ((size_t)(q0 + qq)) * 128 + c16 * 8)) =
        *((const uint4*)(&LT[qq * 128 + c16 * 8]));
  }
}

// ---- S-kernel: P[b][nblk][q][32n] fp16 (swizzled) + lpart colsums.
// XCD co-location: xcd = wgid&7 owns a contiguous 51/50-nunit range (per b).
__global__ __launch_bounds__(256) void k_S(const _Float16* __restrict__ mkp,
                                           const _Float16* __restrict__ qp,
                                           const float* __restrict__ bsq,
                                           const float* __restrict__ ms,
                                           _Float16* __restrict__ P,
                                           float* __restrict__ lpart,
                                           int bBase) {
  const int wgid = blockIdx.x;
  const int xcd = wgid & 7;
  int kk = wgid >> 3;
  const int bg = kk / 867;
  kk -= bg * 867;
  const int nloc = kk / 17, qt = kk % 17;
  const int cntn = (xcd < 5) ? 51 : 50;
  if (nloc >= cntn) return;
  const int base = (xcd < 5) ? xcd * 51 : 255 + (xcd - 5) * 50;
  const int nunit = base + nloc;
  const int n0 = nunit * 64, q0 = qt * 96;

  const _Float16* mkpb = mkp + (size_t)bg * MKP_STRIDE;
  const _Float16* qpb  = qp + (size_t)bg * QP_STRIDE;
  const float* bsqb    = bsq + (size_t)bg * BSQ_STRIDE;
  const float* msb     = ms + (size_t)(bBase + bg) * NTOT;
  _Float16* Pb         = P + (size_t)bg * P_STRIDE;
  float* lpb           = lpart + (size_t)bg * LP_STRIDE;

  const int t = threadIdx.x;
  const int w = t >> 6, l = t & 63, l15 = l & 15, g = l >> 4;
  const int ns = w >> 1, qs = w & 1;

  f16x8 qf[3][4]; float bq[3];
  #pragma unroll
  for (int qi = 0; qi < 3; ++qi) {
    int q = q0 + qs * 48 + qi * 16 + l15;
    #pragma unroll
    for (int ks = 0; ks < 4; ++ks)
      qf[qi][ks] = *((const f16x8*)(qpb + (size_t)q * 128 + (ks * 4 + g) * 8));
    bq[qi] = bsqb[q];
  }
  f16x8 af[2][4];
  #pragma unroll
  for (int nt = 0; nt < 2; ++nt) {
    int n = n0 + ns * 32 + nt * 16 + l15;
    #pragma unroll
    for (int ks = 0; ks < 4; ++ks)
      af[nt][ks] = *((const f16x8*)(mkpb + (size_t)n * 128 + (ks * 4 + g) * 8));
  }
  f32x4 sacc[2][3];
  #pragma unroll
  for (int nt = 0; nt < 2; ++nt)
    #pragma unroll
    for (int qi = 0; qi < 3; ++qi) sacc[nt][qi] = (f32x4)0.f;
  #pragma unroll
  for (int ks = 0; ks < 4; ++ks)
    #pragma unroll
    for (int nt = 0; nt < 2; ++nt)
      #pragma unroll
      for (int qi = 0; qi < 3; ++qi)
        sacc[nt][qi] = __builtin_amdgcn_mfma_f32_16x16x32_f16(af[nt][ks], qf[qi][ks], sacc[nt][qi], 0, 0, 0);

  const float K = 0.125f * 1.44269504f;
  float4 mm[2];
  #pragma unroll
  for (int nt = 0; nt < 2; ++nt)
    mm[nt] = *((const float4*)(msb + n0 + ns * 32 + nt * 16 + g * 4));
  float psum[3] = {0.f, 0.f, 0.f};
  #pragma unroll
  for (int nt = 0; nt < 2; ++nt) {
    float m0 = mm[nt].x * K, m1 = mm[nt].y * K, m2 = mm[nt].z * K, m3 = mm[nt].w * K;
    #pragma unroll
    for (int qi = 0; qi < 3; ++qi) {
      int q = q0 + qs * 48 + qi * 16 + l15;
      float bqv = bq[qi];
      float p0 = exp2f((sacc[nt][qi][0] - bqv) * m0);
      float p1 = exp2f((sacc[nt][qi][1] - bqv) * m1);
      float p2 = exp2f((sacc[nt][qi][2] - bqv) * m2);
      float p3 = exp2f((sacc[nt][qi][3] - bqv) * m3);
      psum[qi] += (p0 + p1) + (p2 + p3);
      f16x4 ph;
      ph[0]=(_Float16)p0; ph[1]=(_Float16)p1; ph[2]=(_Float16)p2; ph[3]=(_Float16)p3;
      int nblkP = nunit * 2 + ns;
      int s_lin = nt * 2 + (g >> 1);
      int s = s_lin ^ ((q >> 1) & 3);
      *((f16x4*)(Pb + ((size_t)nblkP * QPAD + q) * 32 + s * 8 + (g & 1) * 4)) = ph;
    }
  }
  #pragma unroll
  for (int qi = 0; qi < 3; ++qi) {
    psum[qi] += __shfl_xor(psum[qi], 16);
    psum[qi] += __shfl_xor(psum[qi], 32);
  }
  __shared__ float LR[2][96];
  if (g == 0) {
    #pragma unroll
    for (int qi = 0; qi < 3; ++qi) LR[ns][qs * 48 + qi * 16 + l15] = psum[qi];
  }
  __syncthreads();
  if (t < 96) lpb[(size_t)nunit * QPAD + q0 + t] = LR[0][t] + LR[1][t];
}

// ---- lsum: l[b][q] = sum over 405 partials
__global__ __launch_bounds__(256) void k_lsum(const float* __restrict__ lpart,
                                              float* __restrict__ lout) {
  const int bg = blockIdx.y;
  int q = blockIdx.x * 256 + threadIdx.x;
  if (q >= QPAD) return;
  const float* lpb = lpart + (size_t)bg * LP_STRIDE;
  float s = 0.f;
  #pragma unroll 5
  for (int i = 0; i < 405; ++i) s += lpb[(size_t)i * QPAD + q];
  lout[(size_t)bg * LQ_STRIDE + q] = s;
}

// ---- RO: GEMM pO[b][ksp][1024v][1632q] fp16 = MV x P over ksp's K-split.
// R12 geometry verbatim (128v x 96q block, wave 64v x 48q, acc[4][3]).
// KSP=4; XCD co-location pairs (bg,ksp): xcd = bg*4+ksp when NB=2, so each
// XCD streams one disjoint (b, K-range) — same L2 window as R12.
__global__ __launch_bounds__(256) void k_RO(const _Float16* __restrict__ mv2,
                                            const _Float16* __restrict__ P,
                                            _Float16* __restrict__ pO, int NB) {
  const int wgid = blockIdx.x;
  int bg, ksp, kk;
  if (NB == 2) {
    const int xcd = wgid & 7;
    bg = xcd >> 2; ksp = xcd & 3; kk = wgid >> 3;   // kk in 0..135
  } else {
    bg = 0; ksp = wgid & 3; kk = wgid >> 2;
  }
  const int qt = kk % 17, vblk = kk / 17;
  const int mn = (ksp < 2) ? ksp : 2;
  const int start = ksp * 202 + mn;
  const int cnt = 202 + (ksp < 2 ? 1 : 0);

  const _Float16* mv2b = mv2 + (size_t)bg * MV2_STRIDE;
  const _Float16* Pb   = P + (size_t)bg * P_STRIDE;
  _Float16* pOb        = pO + (size_t)bg * PO_STRIDE;

  const int t = threadIdx.x;
  const int w = t >> 6, l = t & 63, l15 = l & 15, g = l >> 4;
  const int wv = w >> 1, wq = w & 1;

  __shared__ _Float16 As[2][4096];   // [128v][32n] linear, pre-swizzled src
  __shared__ _Float16 Bs[2][3072];   // [96q][32n]

  f32x4 acc[4][3];
  #pragma unroll
  for (int i = 0; i < 4; ++i)
    #pragma unroll
    for (int j = 0; j < 3; ++j) acc[i][j] = (f32x4)0.f;

  auto stage = [&](int nblk, int buf) {
    const char* a = (const char*)(mv2b + ((size_t)(vblk * NBLK + nblk)) * 4096);
    char* da = (char*)As[buf];
    gload_lds16(a + t * 16, da + t * 16);
    gload_lds16(a + 4096 + t * 16, da + 4096 + t * 16);
    const char* bsrc = (const char*)(Pb + ((size_t)nblk * QPAD + qt * 96) * 32);
    char* db = (char*)Bs[buf];
    gload_lds16(bsrc + t * 16, db + t * 16);
    if (t < 128) gload_lds16(bsrc + 4096 + t * 16, db + 4096 + t * 16);
  };

  stage(start, 0);
  asm volatile("s_waitcnt vmcnt(0)" ::: "memory");
  __builtin_amdgcn_s_barrier();
  __builtin_amdgcn_sched_barrier(0);

  for (int it = 0; it < cnt; ++it) {
    const int cur = it & 1, nxt = cur ^ 1;
    if (it + 1 < cnt) stage(start + it + 1, nxt);
    const _Float16* Ac = As[cur];
    const _Float16* Bc = Bs[cur];
    f16x8 av[4], bp[3];
    #pragma unroll
    for (int i = 0; i < 4; ++i) {
      int v_loc = wv * 64 + i * 16 + l15;
      av[i] = *((const f16x8*)(Ac + v_loc * 32 + ((g ^ ((v_loc >> 1) & 3)) * 8)));
    }
    #pragma unroll
    for (int j = 0; j < 3; ++j) {
      int q_loc = wq * 48 + j * 16 + l15;
      bp[j] = *((const f16x8*)(Bc + q_loc * 32 + ((g ^ ((q_loc >> 1) & 3)) * 8)));
    }
    #pragma unroll
    for (int i = 0; i < 4; ++i)
      #pragma unroll
      for (int j = 0; j < 3; ++j)
        acc[i][j] = __builtin_amdgcn_mfma_f32_16x16x32_f16(av[i], bp[j], acc[i][j], 0, 0, 0);
    asm volatile("s_waitcnt vmcnt(0) lgkmcnt(0)" ::: "memory");
    __builtin_amdgcn_s_barrier();
    __builtin_amdgcn_sched_barrier(0);
  }

  #pragma unroll
  for (int i = 0; i < 4; ++i) {
    #pragma unroll
    for (int j = 0; j < 3; ++j) {
      int qg = qt * 96 + wq * 48 + j * 16 + l15;
      #pragma unroll
      for (int r = 0; r < 4; ++r) {
        int v = vblk * 128 + wv * 64 + i * 16 + g * 4 + r;
        pOb[((size_t)ksp * OCV + v) * QPAD + qg] = (_Float16)acc[i][j][r];
      }
    }
  }
}

// ---- final: out[b][v][q] = sum_sp pO / l[q]
__global__ __launch_bounds__(256) void k_final(const _Float16* __restrict__ pO,
                                               const float* __restrict__ lq,
                                               float* __restrict__ out,
                                               int bBase) {
  int i = blockIdx.x * 256 + threadIdx.x;
  int q = i % HW;
  int rest = i / HW;
  int v = rest & (OCV - 1);
  int bg = rest >> 10;
  const _Float16* pOb = pO + (size_t)bg * PO_STRIDE;
  float s = 0.f;
  #pragma unroll
  for (int sp = 0; sp < KSP; ++sp)
    s += (float)pOb[((size_t)sp * OCV + v) * QPAD + q];
  out[((size_t)(bBase + bg) * OCV + v) * HW + q] = s / lq[(size_t)bg * LQ_STRIDE + q];
}

static void run_batch(const float* qk, const float* qe, const float* mk,
                      const float* ms, const float* mv, float* out,
                      char* ws, int bBase, int NB, hipStream_t stream) {
  char* p = ws;
  _Float16* mv2 = (_Float16*)p; p += (size_t)NB * MV2_STRIDE * 2;
  _Float16* mkp = (_Float16*)p; p += (size_t)NB * MKP_STRIDE * 2;
  _Float16* qp  = (_Float16*)p; p += (size_t)NB * QP_STRIDE * 2;
  float* bsq    = (float*)p;    p += (size_t)NB * BSQ_STRIDE * 4;
  _Float16* P   = (_Float16*)p; p += (size_t)NB * P_STRIDE * 2;
  _Float16* pO  = (_Float16*)p; p += (size_t)NB * PO_STRIDE * 2;
  float* lpart  = (float*)p;    p += (size_t)NB * LP_STRIDE * 4;
  float* lq     = (float*)p;

  k_prep_mv2<<<dim3(NBLK, 8, NB), 256, 0, stream>>>(mv, mv2, bBase);
  k_prep_mk<<<dim3(405, NB), 256, 0, stream>>>(mk, mkp, bBase);
  k_prep_q<<<dim3(13, NB), 128, 0, stream>>>(qk, qe, qp, bsq, bBase);
  k_S<<<8 * 867 * NB, 256, 0, stream>>>(mkp, qp, bsq, ms, P, lpart, bBase);
  k_lsum<<<dim3(7, NB), 256, 0, stream>>>(lpart, lq);
  k_RO<<<KSP * 136 * NB, 256, 0, stream>>>(mv2, P, pO, NB);
  k_final<<<6480 * NB, 256, 0, stream>>>(pO, lq, out, bBase);
}

extern "C" void kernel_launch(void* const* d_in, const int* in_sizes, int n_in,
                              void* d_out, int out_size, void* d_ws, size_t ws_size,
                              hipStream_t stream) {
  const float* qk = (const float*)d_in[0];
  const float* qe = (const float*)d_in[1];
  const float* mk = (const float*)d_in[2];
  const float* ms = (const float*)d_in[3];
  const float* mv = (const float*)d_in[4];
  float* out = (float*)d_out;

  const size_t per_b = MV2_STRIDE * 2 + MKP_STRIDE * 2 + QP_STRIDE * 2 + BSQ_STRIDE * 4
                     + P_STRIDE * 2 + PO_STRIDE * 2 + LP_STRIDE * 4 + LQ_STRIDE * 4;
  if (ws_size >= 2 * per_b) {
    run_batch(qk, qe, mk, ms, mv, out, (char*)d_ws, 0, 2, stream);
  } else if (ws_size >= per_b) {
    run_batch(qk, qe, mk, ms, mv, out, (char*)d_ws, 0, 1, stream);
    run_batch(qk, qe, mk, ms, mv, out, (char*)d_ws, 1, 1, stream);
  }
}